// Round 4
// baseline (8397.210 us; speedup 1.0000x reference)
//
#include <hip/hip_runtime.h>
#include <cstdint>
#include <cstddef>

// ============================================================================
// EFLSTM: concat(x_text,x_audio,x_vision) -> LSTM(H=1024, T=256, B=256) -> MLP
//
// Round 4: per-lane global loads of A kept getting latency-serialized by the
// compiler (R2 hint: VGPR=56; R3 barrier-pinning: VGPR=108 — barriers don't
// pin non-atomic loads at IR level). Mechanism change:
//   - A (h-tile) staged global->LDS with __builtin_amdgcn_global_load_lds
//     width=16 (side-effecting intrinsic: cannot be sunk; zero VGPR cost;
//     128 async issues/block, one vmcnt drain). Also dedups A across the two
//     nw-waves (halves L2 A-traffic).
//   - W_hh slice moves LDS -> REGISTERS (64 short8 = 256 VGPR/wave, loaded
//     once per chunk, loop-invariant). LDS freed for the A tile.
// LDS: A 128 KB + gates 17 KB = 148480 B (unchanged). 1 block/CU.
// ============================================================================

typedef __attribute__((ext_vector_type(8))) short short8;   // 8 x bf16
typedef __attribute__((ext_vector_type(4))) float f32x4;

#define MFMA_BF16(A,B,C) __builtin_amdgcn_mfma_f32_16x16x32_bf16((A),(B),(C),0,0,0)

// ---- workspace layout (bytes) ----
#define OFF_FLAGS 0u            // 256 * 4
#define OFF_HBUF0 4096u         // 256*1024*2 = 524288   (A-frag-linear bf16)
#define OFF_CBUF  528384u       // 256*1024*4 = 1048576  (fp32 cell state)
#define ZERO_SPAN 1576960u      // flags + hbuf0 + cbuf zeroed every launch
#define OFF_HBUF1 1576960u      // 524288
#define OFF_HFIN  2101248u      // 256*1024*4 = 1048576  (fp32 h_last)
#define OFF_HID   3149824u      // 256*512*4  = 524288   (fp32 mlp hidden)
#define OFF_BIAS  3674112u      // 4096*4
#define OFF_WHH   3690496u      // 64 slices * 64*1024 * 2 = 8388608
#define OFF_WIH   12079104u     // 256*13*64*8*2 = 3407872
#define OFF_XB    15486976u     // 4096*13*64*8*2 = 54525952
#define OFF_XG    70012928u     // 32*256*16*64*8 = 67108864 (bf16 C-frags)
#define WS_NEED   137121792ull

static __device__ __forceinline__ uint16_t f2bf(float f) {
  uint32_t u = __builtin_bit_cast(uint32_t, f);
  uint32_t r = u + 0x7FFFu + ((u >> 16) & 1u);   // round-nearest-even
  return (uint16_t)(r >> 16);
}
static __device__ __forceinline__ float bf2f_lo(uint32_t u) {
  return __builtin_bit_cast(float, u << 16);
}
static __device__ __forceinline__ float bf2f_hi(uint32_t u) {
  return __builtin_bit_cast(float, u & 0xFFFF0000u);
}
static __device__ __forceinline__ float sigm(float x) {
  return 1.0f / (1.0f + __expf(-x));
}
static __device__ __forceinline__ float tanh_f(float x) {
  float e = __expf(2.0f * x);
  return 1.0f - 2.0f / (e + 1.0f);
}
// async global->LDS, 16B per lane; lds dst must be wave-uniform (base+lane*16)
static __device__ __forceinline__ void gld_lds16(const void* gsrc, void* ldst) {
  __builtin_amdgcn_global_load_lds(
      (const __attribute__((address_space(1))) uint32_t*)gsrc,
      (__attribute__((address_space(3))) uint32_t*)ldst, 16, 0, 0);
}

// ---------------------------------------------------------------------------
// pack x (3 tensors, fp32 [B,T,D_i]) -> xb bf16 A-frag-linear:
//   [mtile 4096][ks 13][lane 64][8], m = t*256+b, k padded to 416 with zeros
// ---------------------------------------------------------------------------
__global__ __launch_bounds__(256) void pack_xb_kernel(
    const float* __restrict__ xt, const float* __restrict__ xa,
    const float* __restrict__ xv, uint16_t* __restrict__ xb)
{
  int id = blockIdx.x * 256 + threadIdx.x;          // < 4096*13*64 = 3407872
  int lane = id & 63;
  int rem  = id >> 6;
  int ks = rem % 13;
  int mt = rem / 13;
  int m = mt * 16 + (lane & 15);
  int t = m >> 8;
  int b = m & 255;
  int k0 = ks * 32 + (lane >> 4) * 8;
  size_t base = (size_t)b * 256 + t;
  uint16_t vals[8];
#pragma unroll
  for (int e = 0; e < 8; ++e) {
    int k = k0 + e;
    float v;
    if (k < 300)      v = xt[base * 300 + k];
    else if (k < 374) v = xa[base * 74  + (k - 300)];
    else if (k < 409) v = xv[base * 35  + (k - 374)];
    else              v = 0.0f;
    vals[e] = f2bf(v);
  }
  uint32_t* d32 = (uint32_t*)(xb + (size_t)id * 8);
#pragma unroll
  for (int i = 0; i < 4; ++i)
    d32[i] = (uint32_t)vals[2*i] | ((uint32_t)vals[2*i+1] << 16);
}

// ---------------------------------------------------------------------------
// pack W_hh fp32 [4096,1024] -> bf16 B-frag-linear per scan block s:
//   [s 64][q 4][ks 32][lane 64][8], row = q*1024 + 16*s + (lane&15)
// ---------------------------------------------------------------------------
__global__ __launch_bounds__(256) void pack_whh_kernel(
    const float* __restrict__ whh, uint16_t* __restrict__ wp)
{
  int id = blockIdx.x * 256 + threadIdx.x;          // < 64*4*32*64 = 524288
  int lane = id & 63;
  int ks = (id >> 6) & 31;
  int q  = (id >> 11) & 3;
  int s  = id >> 13;
  int row = q * 1024 + s * 16 + (lane & 15);
  int k0 = ks * 32 + (lane >> 4) * 8;
  const float* src = whh + (size_t)row * 1024 + k0;
  uint16_t vals[8];
#pragma unroll
  for (int e = 0; e < 8; ++e) vals[e] = f2bf(src[e]);
  uint32_t* d32 = (uint32_t*)(wp + (size_t)id * 8);
#pragma unroll
  for (int i = 0; i < 4; ++i)
    d32[i] = (uint32_t)vals[2*i] | ((uint32_t)vals[2*i+1] << 16);
}

// ---------------------------------------------------------------------------
// pack W_ih fp32 [4096,409] -> bf16 B-frag-linear [nt 256][ks 13][lane][8]
// ---------------------------------------------------------------------------
__global__ __launch_bounds__(256) void pack_wih_kernel(
    const float* __restrict__ wih, uint16_t* __restrict__ wp)
{
  int id = blockIdx.x * 256 + threadIdx.x;          // < 256*13*64 = 212992
  int lane = id & 63;
  int rem = id >> 6;
  int ks = rem % 13;
  int nt = rem / 13;
  int n = nt * 16 + (lane & 15);
  int k0 = ks * 32 + (lane >> 4) * 8;
  uint16_t vals[8];
#pragma unroll
  for (int e = 0; e < 8; ++e) {
    int k = k0 + e;
    vals[e] = (k < 409) ? f2bf(wih[(size_t)n * 409 + k]) : (uint16_t)0;
  }
  uint32_t* d32 = (uint32_t*)(wp + (size_t)id * 8);
#pragma unroll
  for (int i = 0; i < 4; ++i)
    d32[i] = (uint32_t)vals[2*i] | ((uint32_t)vals[2*i+1] << 16);
}

__global__ __launch_bounds__(256) void pack_bias_kernel(
    const float* __restrict__ b_ih, const float* __restrict__ b_hh,
    float* __restrict__ bias)
{
  int id = blockIdx.x * 256 + threadIdx.x;          // < 4096
  bias[id] = b_ih[id] + b_hh[id];
}

// ---------------------------------------------------------------------------
// xg GEMM for one 32-step chunk: M=8192 (m=t*256+b), N=4096, K=416 (13 ksteps)
// grid (64, 32), 4 waves, wave tile 64x64 (4x4 of 16x16x32). A/B read directly
// from L2 (both pre-packed frag-linear). C written C-frag-linear bf16 (uint2):
//   [t 32][nt 256][bt 16][lane 64][bf16x4]
// ---------------------------------------------------------------------------
__global__ __launch_bounds__(256) void xg_gemm_kernel(
    const short8* __restrict__ xb, const short8* __restrict__ wih,
    const float* __restrict__ bias, uint2* __restrict__ xg, int chunk)
{
  int tid = threadIdx.x;
  int lane = tid & 63;
  int w = tid >> 6;
  int wm = w & 1, wn = w >> 1;
  int bm = blockIdx.x, bn = blockIdx.y;
  int mtb = bm * 8 + wm * 4;          // local mtile base, 0..511
  int ntb = bn * 8 + wn * 4;          // ntile base, 0..255
  int col = lane & 15;

  f32x4 acc[4][4];
#pragma unroll
  for (int b = 0; b < 4; ++b) {
    float bv = bias[(ntb + b) * 16 + col];
    f32x4 v = {bv, bv, bv, bv};
#pragma unroll
    for (int a = 0; a < 4; ++a) acc[a][b] = v;
  }
  size_t mt_glob = (size_t)chunk * 512 + mtb;
  for (int ks = 0; ks < 13; ++ks) {
    short8 Af[4], Bf[4];
#pragma unroll
    for (int a = 0; a < 4; ++a)
      Af[a] = xb[((mt_glob + a) * 13 + ks) * 64 + lane];
#pragma unroll
    for (int b = 0; b < 4; ++b)
      Bf[b] = wih[(((size_t)(ntb + b)) * 13 + ks) * 64 + lane];
#pragma unroll
    for (int a = 0; a < 4; ++a)
#pragma unroll
      for (int b = 0; b < 4; ++b)
        acc[a][b] = MFMA_BF16(Af[a], Bf[b], acc[a][b]);
  }
#pragma unroll
  for (int a = 0; a < 4; ++a) {
    int mt = mtb + a;
    int t_loc = mt >> 4;
    int bt = mt & 15;
#pragma unroll
    for (int b = 0; b < 4; ++b) {
      size_t idx = (((size_t)t_loc * 256 + (ntb + b)) * 16 + bt) * 64 + lane;
      f32x4 v = acc[a][b];
      uint2 o;
      o.x = (uint32_t)f2bf(v[0]) | ((uint32_t)f2bf(v[1]) << 16);
      o.y = (uint32_t)f2bf(v[2]) | ((uint32_t)f2bf(v[3]) << 16);
      xg[idx] = o;
    }
  }
}

// ---------------------------------------------------------------------------
// Persistent scan: 256 blocks x 256 threads, 1 block/CU.
// group g = bid>>6 owns batch rows [64g,64g+64); slice s = bid&63 owns hidden
// units [16s,16s+16). W_hh B-frags REGISTER-resident (2 ntiles x 32 ks x 16B
// = 256 VGPR/wave, loaded once per chunk). Per step:
//   issue 128 global_load_lds (A h-tile, 128 KB, 32/wave) -> S1 (vmcnt drain)
//   fully-unrolled ds_read_b128 + MFMA (B from regs) -> gates->LDS -> S3
//   elementwise (c in regs) -> h' 8B agent store -> S4 -> flag release
//   -> xg prefetch -> all-thread poll + acquire -> S5
// ---------------------------------------------------------------------------
__global__ __launch_bounds__(256, 1) void scan_kernel(
    const uint16_t* __restrict__ whh_p, const uint2* __restrict__ xg,
    uint16_t* __restrict__ hbuf0, uint16_t* __restrict__ hbuf1,
    float* __restrict__ c_buf, float* __restrict__ h_final,
    uint32_t* flags, int chunk)
{
  extern __shared__ char smem[];
  // smem[0      .. 131072): A tile, 4 mtiles x 32 ks x 64 lanes x 16 B
  // smem[131072 .. 148480): gate exchange, [64][68] fp32
  float* gl = (float*)(smem + 131072);

  const int tid = threadIdx.x;
  const int bid = blockIdx.x;
  const int g = bid >> 6, s = bid & 63;
  const int lane = tid & 63, w = tid >> 6;
  const int mw = w & 1, nw = w >> 1;

  // ---- W_hh B-frags into registers (once per chunk; loop-invariant) ----
  short8 Wr0[32], Wr1[32];
  {
    const short8* wsrc = (const short8*)whh_p + (size_t)s * 4 * 32 * 64;
#pragma unroll
    for (int ks = 0; ks < 32; ++ks)
      Wr0[ks] = wsrc[(((nw * 2 + 0) * 32) + ks) * 64 + lane];
#pragma unroll
    for (int ks = 0; ks < 32; ++ks)
      Wr1[ks] = wsrc[(((nw * 2 + 1) * 32) + ks) * 64 + lane];
  }

  // elementwise ownership: thread handles units col_e..col_e+3 of row R_e
  const int row_e = tid >> 2;                // 0..63
  const int j_e = (tid & 3) * 4;             // 0,4,8,12
  const int R_e = g * 64 + row_e;
  const int col_e = s * 16 + j_e;            // hidden col base
  f32x4 c4 = *(const f32x4*)(c_buf + (size_t)R_e * 1024 + col_e);

  // precompute h'-store address (4 consecutive bf16 = one aligned 8B store)
  size_t hstore_base;
  {
    int cg0 = col_e;
    int ksh = cg0 >> 5, quad = (cg0 >> 3) & 3, e0 = cg0 & 7;
    int mth = row_e >> 4;
    int laneh = quad * 16 + (row_e & 15);
    hstore_base = (((size_t)(g * 4 + mth) * 32 + ksh) * 64 + laneh) * 8 + e0;
  }

  const short8* Afrag = (const short8*)smem;
  const int myflag = g * 64 + (tid & 63);

  // xg prefetch for step 0 (bf16 C-frags, 8B per (a,b))
  uint2 xp[2][2];
#pragma unroll
  for (int a = 0; a < 2; ++a)
#pragma unroll
    for (int b = 0; b < 2; ++b) {
      int q = nw * 2 + b;
      size_t idx = (((size_t)0 * 256 + (q * 64 + s)) * 16 + (g * 4 + mw * 2 + a)) * 64 + lane;
      xp[a][b] = xg[idx];
    }

  for (int l = 0; l < 32; ++l) {
    const int ts = chunk * 32 + l;
    const uint16_t* hin = (ts & 1) ? hbuf1 : hbuf0;
    uint16_t* hout = (ts & 1) ? hbuf0 : hbuf1;

    // ---- stage this step's A h-tile into LDS: 128 x (1 KB), 32 per wave ----
    {
      const uint16_t* gbase = hin + (size_t)g * 65536
                              + (size_t)(w * 32) * 512 + (size_t)lane * 8;
      char* lbase = smem + (size_t)(w * 32) * 1024;
#pragma unroll
      for (int p = 0; p < 32; ++p)
        gld_lds16(gbase + (size_t)p * 512, lbase + p * 1024);
    }

    // acc init from prefetched bf16 xg (bias folded in at gemm time)
    f32x4 acc[2][2];
#pragma unroll
    for (int a = 0; a < 2; ++a)
#pragma unroll
      for (int b = 0; b < 2; ++b) {
        uint2 p = xp[a][b];
        f32x4 v = {bf2f_lo(p.x), bf2f_hi(p.x), bf2f_lo(p.y), bf2f_hi(p.y)};
        acc[a][b] = v;
      }

    __syncthreads();   // S1: vmcnt(0) drain -> A tile fully in LDS

    // ---- fully unrolled: A from LDS (ds_read_b128), B from registers ----
#pragma unroll
    for (int ks = 0; ks < 32; ++ks) {
      short8 A0 = Afrag[((mw * 2 + 0) * 32 + ks) * 64 + lane];
      short8 A1 = Afrag[((mw * 2 + 1) * 32 + ks) * 64 + lane];
      acc[0][0] = MFMA_BF16(A0, Wr0[ks], acc[0][0]);
      acc[0][1] = MFMA_BF16(A0, Wr1[ks], acc[0][1]);
      acc[1][0] = MFMA_BF16(A1, Wr0[ks], acc[1][0]);
      acc[1][1] = MFMA_BF16(A1, Wr1[ks], acc[1][1]);
    }

    // gates -> LDS  (C layout: col=lane&15, row=(lane>>4)*4+reg)
    {
      int r0 = (lane >> 4) * 4;
      int cc = lane & 15;
#pragma unroll
      for (int a = 0; a < 2; ++a)
#pragma unroll
        for (int b = 0; b < 2; ++b) {
          int row = (mw * 2 + a) * 16 + r0;
          int colc = (nw * 2 + b) * 16 + cc;
#pragma unroll
          for (int r = 0; r < 4; ++r)
            gl[(row + r) * 68 + colc] = acc[a][b][r];
        }
    }
    __syncthreads();   // S3: gates visible (A-tile reads also complete)
    // LSTM elementwise (PyTorch gate order i,f,g,o)
    float hv[4];
#pragma unroll
    for (int u = 0; u < 4; ++u) {
      int cj = j_e + u;
      float xi = gl[row_e * 68 + cj];
      float xf = gl[row_e * 68 + 16 + cj];
      float xg_ = gl[row_e * 68 + 32 + cj];
      float xo = gl[row_e * 68 + 48 + cj];
      float cn = sigm(xf) * c4[u] + sigm(xi) * tanh_f(xg_);
      c4[u] = cn;
      hv[u] = sigm(xo) * tanh_f(cn);
    }
    // h' as ONE 8-byte agent-scope store
    {
      uint32_t w0 = (uint32_t)f2bf(hv[0]) | ((uint32_t)f2bf(hv[1]) << 16);
      uint32_t w1 = (uint32_t)f2bf(hv[2]) | ((uint32_t)f2bf(hv[3]) << 16);
      unsigned long long v = ((unsigned long long)w1 << 32) | w0;
      __hip_atomic_store((unsigned long long*)(hout + hstore_base), v,
                         __ATOMIC_RELAXED, __HIP_MEMORY_SCOPE_AGENT);
    }
    if (chunk == 7 && l == 31) {
      f32x4 hh = {hv[0], hv[1], hv[2], hv[3]};
      *(f32x4*)(h_final + (size_t)R_e * 1024 + col_e) = hh;
    }
    if (l != 31) {
      // ---- group-local barrier over the 64 blocks sharing batch group g ----
      __syncthreads();                       // S4: drains all waves' h' stores
      if (tid == 0) {
        __threadfence();                     // agent release
        __hip_atomic_store(&flags[bid], (uint32_t)(ts + 1),
                           __ATOMIC_RELEASE, __HIP_MEMORY_SCOPE_AGENT);
      }
      // prefetch next step's xg while waiting on the barrier (xg constant)
      {
        int ln = l + 1;
#pragma unroll
        for (int a = 0; a < 2; ++a)
#pragma unroll
          for (int b = 0; b < 2; ++b) {
            int q = nw * 2 + b;
            size_t idx = (((size_t)ln * 256 + (q * 64 + s)) * 16 + (g * 4 + mw * 2 + a)) * 64 + lane;
            xp[a][b] = xg[idx];
          }
      }
      // all threads poll (one flag per lane) then acquire-fence: every
      // consumer wave owns its own acquire before the global_load_lds reads
      while (__hip_atomic_load(&flags[myflag], __ATOMIC_RELAXED,
                               __HIP_MEMORY_SCOPE_AGENT) < (uint32_t)(ts + 1)) {
        __builtin_amdgcn_s_sleep(1);
      }
      __threadfence();                       // agent acquire
      __syncthreads();                       // S5
    }
  }
  *(f32x4*)(c_buf + (size_t)R_e * 1024 + col_e) = c4;
}

// ---------------------------------------------------------------------------
// MLP layer 1: hidden = relu(h_last @ W1^T + b1), fp32 VALU.
// ---------------------------------------------------------------------------
__global__ __launch_bounds__(256) void mlp1_kernel(
    const float* __restrict__ h_final, const float* __restrict__ W1,
    const float* __restrict__ b1, float* __restrict__ hidden)
{
  __shared__ float hl[8 * 1024];       // 32 KB
  __shared__ float part[4 * 64 * 8];   // 8 KB
  int tid = threadIdx.x;
  int rb = blockIdx.x;                 // 0..31
  int cb = blockIdx.y;                 // 0..7
  const f32x4* hsrc = (const f32x4*)(h_final + (size_t)rb * 8 * 1024);
  for (int i = tid; i < 2048; i += 256) ((f32x4*)hl)[i] = hsrc[i];
  __syncthreads();
  int cell_l = tid & 63;
  int kq = tid >> 6;                   // k quarter
  int cell = cb * 64 + cell_l;
  float accv[8] = {0,0,0,0,0,0,0,0};
  const f32x4* wrow = (const f32x4*)(W1 + (size_t)cell * 1024) + kq * 64;
  const f32x4* hl4 = (const f32x4*)hl;
  for (int k4 = 0; k4 < 64; ++k4) {
    f32x4 wv = wrow[k4];
    int kidx = kq * 64 + k4;
#pragma unroll
    for (int r = 0; r < 8; ++r) {
      f32x4 hv = hl4[r * 256 + kidx];
      accv[r] += wv[0] * hv[0] + wv[1] * hv[1] + wv[2] * hv[2] + wv[3] * hv[3];
    }
  }
#pragma unroll
  for (int r = 0; r < 8; ++r) part[(kq * 64 + cell_l) * 8 + r] = accv[r];
  __syncthreads();
#pragma unroll
  for (int rr = 0; rr < 2; ++rr) {
    int r = kq * 2 + rr;
    float sum = b1[cell];
    for (int q = 0; q < 4; ++q) sum += part[(q * 64 + cell_l) * 8 + r];
    hidden[(size_t)(rb * 8 + r) * 512 + cell] = fmaxf(sum, 0.0f);
  }
}

// MLP layer 2: out[b] = hidden[b] . W2 + b2
__global__ __launch_bounds__(256) void mlp2_kernel(
    const float* __restrict__ hidden, const float* __restrict__ W2,
    const float* __restrict__ b2, float* __restrict__ out)
{
  __shared__ float w2l[512];
  int tid = threadIdx.x;
  for (int i = tid; i < 512; i += 256) w2l[i] = W2[i];
  __syncthreads();
  const f32x4* hrow = (const f32x4*)(hidden + (size_t)tid * 512);
  const f32x4* w4 = (const f32x4*)w2l;
  float acc = b2[0];
  for (int k = 0; k < 128; ++k) {
    f32x4 a = hrow[k], b = w4[k];
    acc += a[0] * b[0] + a[1] * b[1] + a[2] * b[2] + a[3] * b[3];
  }
  out[tid] = acc;
}

// ---------------------------------------------------------------------------
extern "C" void kernel_launch(void* const* d_in, const int* in_sizes, int n_in,
                              void* d_out, int out_size, void* d_ws, size_t ws_size,
                              hipStream_t stream)
{
  (void)in_sizes; (void)n_in; (void)out_size;
  if (ws_size < WS_NEED) return;   // workspace too small -> loud bench failure

  const float* xt   = (const float*)d_in[0];
  const float* xa   = (const float*)d_in[1];
  const float* xv   = (const float*)d_in[2];
  const float* W_ih = (const float*)d_in[3];
  const float* W_hh = (const float*)d_in[4];
  const float* b_ih = (const float*)d_in[5];
  const float* b_hh = (const float*)d_in[6];
  const float* W1   = (const float*)d_in[7];
  const float* b1   = (const float*)d_in[8];
  const float* W2   = (const float*)d_in[9];
  const float* b2   = (const float*)d_in[10];
  float* out = (float*)d_out;
  char* ws = (char*)d_ws;

  uint32_t* flags   = (uint32_t*)(ws + OFF_FLAGS);
  uint16_t* hb0     = (uint16_t*)(ws + OFF_HBUF0);
  uint16_t* hb1     = (uint16_t*)(ws + OFF_HBUF1);
  float*    c_buf   = (float*)(ws + OFF_CBUF);
  float*    h_final = (float*)(ws + OFF_HFIN);
  float*    hidden  = (float*)(ws + OFF_HID);
  float*    bias    = (float*)(ws + OFF_BIAS);
  uint16_t* whh_p   = (uint16_t*)(ws + OFF_WHH);
  uint16_t* wih_p   = (uint16_t*)(ws + OFF_WIH);
  uint16_t* xb      = (uint16_t*)(ws + OFF_XB);
  uint2*    xg      = (uint2*)(ws + OFF_XG);

  // allow >64KB dynamic LDS for the scan kernel (idempotent, capture-safe)
  hipFuncSetAttribute((const void*)scan_kernel,
                      hipFuncAttributeMaxDynamicSharedMemorySize, 148480);

  // zero flags + h state + c state (ws is poisoned before every launch)
  hipMemsetAsync(ws, 0, ZERO_SPAN, stream);

  pack_xb_kernel  <<<13312, 256, 0, stream>>>(xt, xa, xv, xb);
  pack_whh_kernel <<<2048,  256, 0, stream>>>(W_hh, whh_p);
  pack_wih_kernel <<<832,   256, 0, stream>>>(W_ih, wih_p);
  pack_bias_kernel<<<16,    256, 0, stream>>>(b_ih, b_hh, bias);

  for (int c = 0; c < 8; ++c) {
    xg_gemm_kernel<<<dim3(64, 32), 256, 0, stream>>>(
        (const short8*)xb, (const short8*)wih_p, bias, xg, c);
    scan_kernel<<<256, 256, 148480, stream>>>(
        whh_p, xg, hb0, hb1, c_buf, h_final, flags, c);
  }
  mlp1_kernel<<<dim3(32, 8), 256, 0, stream>>>(h_final, W1, b1, hidden);
  mlp2_kernel<<<1, 256, 0, stream>>>(hidden, W2, b2, out);
}

// Round 5
// 2223.017 us; speedup vs baseline: 3.7774x; 3.7774x over previous
//
#include <hip/hip_runtime.h>
#include <cstdint>
#include <cstddef>

// ============================================================================
// EFLSTM: concat(x_text,x_audio,x_vision) -> LSTM(H=1024, T=256, B=256) -> MLP
//
// Round 5: the per-step __threadfence() (agent acquire/release) was lowering
// to a FULL L2 invalidate per XCD per step -> xg/W/h re-fetched from HBM every
// step (FETCH_SIZE ~100 MB/dispatch in R1-R4 vs ~10 MB true footprint).
// Fence-free design:
//   - h' stores: __hip_atomic_store agent relaxed (write-through to IF);
//     release ordering = the vmcnt(0) drain inside __syncthreads before the
//     flag store.
//   - flags: agent relaxed atomics (IF-coherent).
//   - A-tile: global_load_lds with aux=0x11 (SC0|SC1) -> reads served at the
//     coherence point (IF), never from a stale per-XCD L2 line. 128 KB/step
//     staged into LDS, zero VGPR cost, cannot be sunk by the compiler.
//   - W_hh: plain cached per-step loads (frag-linear) -> stays L2-resident
//     now that nothing invalidates L2. No register file, no LDS residency.
// LDS: A 128 KB + gates 17 KB = 148480 B. 1 block/CU.
// ============================================================================

typedef __attribute__((ext_vector_type(8))) short short8;   // 8 x bf16
typedef __attribute__((ext_vector_type(4))) float f32x4;

#define MFMA_BF16(A,B,C) __builtin_amdgcn_mfma_f32_16x16x32_bf16((A),(B),(C),0,0,0)

// ---- workspace layout (bytes) ----
#define OFF_FLAGS 0u            // 256 * 4
#define OFF_HBUF0 4096u         // 256*1024*2 = 524288   (A-frag-linear bf16)
#define OFF_CBUF  528384u       // 256*1024*4 = 1048576  (fp32 cell state)
#define ZERO_SPAN 1576960u      // flags + hbuf0 + cbuf zeroed every launch
#define OFF_HBUF1 1576960u      // 524288
#define OFF_HFIN  2101248u      // 256*1024*4 = 1048576  (fp32 h_last)
#define OFF_HID   3149824u      // 256*512*4  = 524288   (fp32 mlp hidden)
#define OFF_BIAS  3674112u      // 4096*4
#define OFF_WHH   3690496u      // 64 slices * 64*1024 * 2 = 8388608
#define OFF_WIH   12079104u     // 256*13*64*8*2 = 3407872
#define OFF_XB    15486976u     // 4096*13*64*8*2 = 54525952
#define OFF_XG    70012928u     // 32*256*16*64*8 = 67108864 (bf16 C-frags)
#define WS_NEED   137121792ull

static __device__ __forceinline__ uint16_t f2bf(float f) {
  uint32_t u = __builtin_bit_cast(uint32_t, f);
  uint32_t r = u + 0x7FFFu + ((u >> 16) & 1u);   // round-nearest-even
  return (uint16_t)(r >> 16);
}
static __device__ __forceinline__ float bf2f_lo(uint32_t u) {
  return __builtin_bit_cast(float, u << 16);
}
static __device__ __forceinline__ float bf2f_hi(uint32_t u) {
  return __builtin_bit_cast(float, u & 0xFFFF0000u);
}
static __device__ __forceinline__ float sigm(float x) {
  return 1.0f / (1.0f + __expf(-x));
}
static __device__ __forceinline__ float tanh_f(float x) {
  float e = __expf(2.0f * x);
  return 1.0f - 2.0f / (e + 1.0f);
}
// async global->LDS, 16B/lane, aux=0x11 (SC0|SC1): agent/system-scope read,
// bypasses the non-coherent per-XCD L2 -> always sees peer XCDs' IF stores.
static __device__ __forceinline__ void gld_lds16_coh(const void* gsrc, void* ldst) {
  __builtin_amdgcn_global_load_lds(
      (const __attribute__((address_space(1))) uint32_t*)gsrc,
      (__attribute__((address_space(3))) uint32_t*)ldst, 16, 0, 0x11);
}

// ---------------------------------------------------------------------------
// pack x (3 tensors, fp32 [B,T,D_i]) -> xb bf16 A-frag-linear:
//   [mtile 4096][ks 13][lane 64][8], m = t*256+b, k padded to 416 with zeros
// ---------------------------------------------------------------------------
__global__ __launch_bounds__(256) void pack_xb_kernel(
    const float* __restrict__ xt, const float* __restrict__ xa,
    const float* __restrict__ xv, uint16_t* __restrict__ xb)
{
  int id = blockIdx.x * 256 + threadIdx.x;          // < 4096*13*64 = 3407872
  int lane = id & 63;
  int rem  = id >> 6;
  int ks = rem % 13;
  int mt = rem / 13;
  int m = mt * 16 + (lane & 15);
  int t = m >> 8;
  int b = m & 255;
  int k0 = ks * 32 + (lane >> 4) * 8;
  size_t base = (size_t)b * 256 + t;
  uint16_t vals[8];
#pragma unroll
  for (int e = 0; e < 8; ++e) {
    int k = k0 + e;
    float v;
    if (k < 300)      v = xt[base * 300 + k];
    else if (k < 374) v = xa[base * 74  + (k - 300)];
    else if (k < 409) v = xv[base * 35  + (k - 374)];
    else              v = 0.0f;
    vals[e] = f2bf(v);
  }
  uint32_t* d32 = (uint32_t*)(xb + (size_t)id * 8);
#pragma unroll
  for (int i = 0; i < 4; ++i)
    d32[i] = (uint32_t)vals[2*i] | ((uint32_t)vals[2*i+1] << 16);
}

// ---------------------------------------------------------------------------
// pack W_hh fp32 [4096,1024] -> bf16 B-frag-linear per scan block s:
//   [s 64][q 4][ks 32][lane 64][8], row = q*1024 + 16*s + (lane&15)
// ---------------------------------------------------------------------------
__global__ __launch_bounds__(256) void pack_whh_kernel(
    const float* __restrict__ whh, uint16_t* __restrict__ wp)
{
  int id = blockIdx.x * 256 + threadIdx.x;          // < 64*4*32*64 = 524288
  int lane = id & 63;
  int ks = (id >> 6) & 31;
  int q  = (id >> 11) & 3;
  int s  = id >> 13;
  int row = q * 1024 + s * 16 + (lane & 15);
  int k0 = ks * 32 + (lane >> 4) * 8;
  const float* src = whh + (size_t)row * 1024 + k0;
  uint16_t vals[8];
#pragma unroll
  for (int e = 0; e < 8; ++e) vals[e] = f2bf(src[e]);
  uint32_t* d32 = (uint32_t*)(wp + (size_t)id * 8);
#pragma unroll
  for (int i = 0; i < 4; ++i)
    d32[i] = (uint32_t)vals[2*i] | ((uint32_t)vals[2*i+1] << 16);
}

// ---------------------------------------------------------------------------
// pack W_ih fp32 [4096,409] -> bf16 B-frag-linear [nt 256][ks 13][lane][8]
// ---------------------------------------------------------------------------
__global__ __launch_bounds__(256) void pack_wih_kernel(
    const float* __restrict__ wih, uint16_t* __restrict__ wp)
{
  int id = blockIdx.x * 256 + threadIdx.x;          // < 256*13*64 = 212992
  int lane = id & 63;
  int rem = id >> 6;
  int ks = rem % 13;
  int nt = rem / 13;
  int n = nt * 16 + (lane & 15);
  int k0 = ks * 32 + (lane >> 4) * 8;
  uint16_t vals[8];
#pragma unroll
  for (int e = 0; e < 8; ++e) {
    int k = k0 + e;
    vals[e] = (k < 409) ? f2bf(wih[(size_t)n * 409 + k]) : (uint16_t)0;
  }
  uint32_t* d32 = (uint32_t*)(wp + (size_t)id * 8);
#pragma unroll
  for (int i = 0; i < 4; ++i)
    d32[i] = (uint32_t)vals[2*i] | ((uint32_t)vals[2*i+1] << 16);
}

__global__ __launch_bounds__(256) void pack_bias_kernel(
    const float* __restrict__ b_ih, const float* __restrict__ b_hh,
    float* __restrict__ bias)
{
  int id = blockIdx.x * 256 + threadIdx.x;          // < 4096
  bias[id] = b_ih[id] + b_hh[id];
}

// ---------------------------------------------------------------------------
// xg GEMM for one 32-step chunk: M=8192 (m=t*256+b), N=4096, K=416 (13 ksteps)
// grid (64, 32), 4 waves, wave tile 64x64 (4x4 of 16x16x32). A/B read directly
// from L2 (both pre-packed frag-linear). C written C-frag-linear bf16 (uint2):
//   [t 32][nt 256][bt 16][lane 64][bf16x4]
// ---------------------------------------------------------------------------
__global__ __launch_bounds__(256) void xg_gemm_kernel(
    const short8* __restrict__ xb, const short8* __restrict__ wih,
    const float* __restrict__ bias, uint2* __restrict__ xg, int chunk)
{
  int tid = threadIdx.x;
  int lane = tid & 63;
  int w = tid >> 6;
  int wm = w & 1, wn = w >> 1;
  int bm = blockIdx.x, bn = blockIdx.y;
  int mtb = bm * 8 + wm * 4;          // local mtile base, 0..511
  int ntb = bn * 8 + wn * 4;          // ntile base, 0..255
  int col = lane & 15;

  f32x4 acc[4][4];
#pragma unroll
  for (int b = 0; b < 4; ++b) {
    float bv = bias[(ntb + b) * 16 + col];
    f32x4 v = {bv, bv, bv, bv};
#pragma unroll
    for (int a = 0; a < 4; ++a) acc[a][b] = v;
  }
  size_t mt_glob = (size_t)chunk * 512 + mtb;
  for (int ks = 0; ks < 13; ++ks) {
    short8 Af[4], Bf[4];
#pragma unroll
    for (int a = 0; a < 4; ++a)
      Af[a] = xb[((mt_glob + a) * 13 + ks) * 64 + lane];
#pragma unroll
    for (int b = 0; b < 4; ++b)
      Bf[b] = wih[(((size_t)(ntb + b)) * 13 + ks) * 64 + lane];
#pragma unroll
    for (int a = 0; a < 4; ++a)
#pragma unroll
      for (int b = 0; b < 4; ++b)
        acc[a][b] = MFMA_BF16(Af[a], Bf[b], acc[a][b]);
  }
#pragma unroll
  for (int a = 0; a < 4; ++a) {
    int mt = mtb + a;
    int t_loc = mt >> 4;
    int bt = mt & 15;
#pragma unroll
    for (int b = 0; b < 4; ++b) {
      size_t idx = (((size_t)t_loc * 256 + (ntb + b)) * 16 + bt) * 64 + lane;
      f32x4 v = acc[a][b];
      uint2 o;
      o.x = (uint32_t)f2bf(v[0]) | ((uint32_t)f2bf(v[1]) << 16);
      o.y = (uint32_t)f2bf(v[2]) | ((uint32_t)f2bf(v[3]) << 16);
      xg[idx] = o;
    }
  }
}

// ---------------------------------------------------------------------------
// Persistent scan: 256 blocks x 256 threads, 1 block/CU.
// group g = bid>>6 owns batch rows [64g,64g+64); slice s = bid&63 owns hidden
// units [16s,16s+16). Per step:
//   issue 128 gld_lds16_coh (A h-tile from IF, 128 KB, 32/wave) -> S1
//   unrolled loop: A ds_read_b128, W_hh cached L2 loads, 4 MFMA / ks
//   gates->LDS -> S3 -> elementwise (c in regs) -> h' 8B agent store -> S4
//   (vmcnt drained) -> flag store (relaxed agent) -> xg prefetch -> all-lane
//   poll -> S5. NO cache-wide fences anywhere.
// ---------------------------------------------------------------------------
__global__ __launch_bounds__(256, 1) void scan_kernel(
    const uint16_t* __restrict__ whh_p, const uint2* __restrict__ xg,
    uint16_t* __restrict__ hbuf0, uint16_t* __restrict__ hbuf1,
    float* __restrict__ c_buf, float* __restrict__ h_final,
    uint32_t* flags, int chunk)
{
  extern __shared__ char smem[];
  // smem[0      .. 131072): A tile, 4 mtiles x 32 ks x 64 lanes x 16 B
  // smem[131072 .. 148480): gate exchange, [64][68] fp32
  float* gl = (float*)(smem + 131072);

  const int tid = threadIdx.x;
  const int bid = blockIdx.x;
  const int g = bid >> 6, s = bid & 63;
  const int lane = tid & 63, w = tid >> 6;
  const int mw = w & 1, nw = w >> 1;

  // per-wave W_hh fragment pointers (read from L2 every step; stays hot now)
  const short8* wsrc = (const short8*)whh_p + (size_t)s * 4 * 32 * 64;
  const short8* w0p = wsrc + ((size_t)(nw * 2 + 0) * 32) * 64 + lane;
  const short8* w1p = wsrc + ((size_t)(nw * 2 + 1) * 32) * 64 + lane;

  // elementwise ownership: thread handles units col_e..col_e+3 of row R_e
  const int row_e = tid >> 2;                // 0..63
  const int j_e = (tid & 3) * 4;             // 0,4,8,12
  const int R_e = g * 64 + row_e;
  const int col_e = s * 16 + j_e;            // hidden col base
  f32x4 c4 = *(const f32x4*)(c_buf + (size_t)R_e * 1024 + col_e);

  // precompute h'-store address (4 consecutive bf16 = one aligned 8B store)
  size_t hstore_base;
  {
    int cg0 = col_e;
    int ksh = cg0 >> 5, quad = (cg0 >> 3) & 3, e0 = cg0 & 7;
    int mth = row_e >> 4;
    int laneh = quad * 16 + (row_e & 15);
    hstore_base = (((size_t)(g * 4 + mth) * 32 + ksh) * 64 + laneh) * 8 + e0;
  }

  const short8* Afrag = (const short8*)smem;
  const int myflag = g * 64 + (tid & 63);

  // xg prefetch for step 0 (bf16 C-frags, 8B per (a,b)) — plain cached loads
  uint2 xp[2][2];
#pragma unroll
  for (int a = 0; a < 2; ++a)
#pragma unroll
    for (int b = 0; b < 2; ++b) {
      int q = nw * 2 + b;
      size_t idx = (((size_t)0 * 256 + (q * 64 + s)) * 16 + (g * 4 + mw * 2 + a)) * 64 + lane;
      xp[a][b] = xg[idx];
    }

  for (int l = 0; l < 32; ++l) {
    const int ts = chunk * 32 + l;
    const uint16_t* hin = (ts & 1) ? hbuf1 : hbuf0;
    uint16_t* hout = (ts & 1) ? hbuf0 : hbuf1;

    // ---- stage this step's A h-tile into LDS: 128 x (1 KB), 32 per wave ----
    {
      const uint16_t* gbase = hin + (size_t)g * 65536
                              + (size_t)(w * 32) * 512 + (size_t)lane * 8;
      char* lbase = smem + (size_t)(w * 32) * 1024;
#pragma unroll
      for (int p = 0; p < 32; ++p)
        gld_lds16_coh(gbase + (size_t)p * 512, lbase + p * 1024);
    }

    // acc init from prefetched bf16 xg (bias folded in at gemm time)
    f32x4 acc[2][2];
#pragma unroll
    for (int a = 0; a < 2; ++a)
#pragma unroll
      for (int b = 0; b < 2; ++b) {
        uint2 p = xp[a][b];
        f32x4 v = {bf2f_lo(p.x), bf2f_hi(p.x), bf2f_lo(p.y), bf2f_hi(p.y)};
        acc[a][b] = v;
      }

    __syncthreads();   // S1: vmcnt(0) drain -> A tile fully in LDS

    // ---- unrolled: A from LDS (ds_read_b128), W from L2 (cached loads) ----
#pragma unroll
    for (int ks = 0; ks < 32; ++ks) {
      short8 B0 = w0p[ks * 64];
      short8 B1 = w1p[ks * 64];
      short8 A0 = Afrag[((mw * 2 + 0) * 32 + ks) * 64 + lane];
      short8 A1 = Afrag[((mw * 2 + 1) * 32 + ks) * 64 + lane];
      acc[0][0] = MFMA_BF16(A0, B0, acc[0][0]);
      acc[0][1] = MFMA_BF16(A0, B1, acc[0][1]);
      acc[1][0] = MFMA_BF16(A1, B0, acc[1][0]);
      acc[1][1] = MFMA_BF16(A1, B1, acc[1][1]);
    }

    // gates -> LDS  (C layout: col=lane&15, row=(lane>>4)*4+reg)
    {
      int r0 = (lane >> 4) * 4;
      int cc = lane & 15;
#pragma unroll
      for (int a = 0; a < 2; ++a)
#pragma unroll
        for (int b = 0; b < 2; ++b) {
          int row = (mw * 2 + a) * 16 + r0;
          int colc = (nw * 2 + b) * 16 + cc;
#pragma unroll
          for (int r = 0; r < 4; ++r)
            gl[(row + r) * 68 + colc] = acc[a][b][r];
        }
    }
    __syncthreads();   // S3: gates visible (A-tile reads also complete)
    // LSTM elementwise (PyTorch gate order i,f,g,o)
    float hv[4];
#pragma unroll
    for (int u = 0; u < 4; ++u) {
      int cj = j_e + u;
      float xi = gl[row_e * 68 + cj];
      float xf = gl[row_e * 68 + 16 + cj];
      float xg_ = gl[row_e * 68 + 32 + cj];
      float xo = gl[row_e * 68 + 48 + cj];
      float cn = sigm(xf) * c4[u] + sigm(xi) * tanh_f(xg_);
      c4[u] = cn;
      hv[u] = sigm(xo) * tanh_f(cn);
    }
    // h' as ONE 8-byte agent-scope store (write-through to IF)
    {
      uint32_t w0 = (uint32_t)f2bf(hv[0]) | ((uint32_t)f2bf(hv[1]) << 16);
      uint32_t w1 = (uint32_t)f2bf(hv[2]) | ((uint32_t)f2bf(hv[3]) << 16);
      unsigned long long v = ((unsigned long long)w1 << 32) | w0;
      __hip_atomic_store((unsigned long long*)(hout + hstore_base), v,
                         __ATOMIC_RELAXED, __HIP_MEMORY_SCOPE_AGENT);
    }
    if (chunk == 7 && l == 31) {
      f32x4 hh = {hv[0], hv[1], hv[2], hv[3]};
      *(f32x4*)(h_final + (size_t)R_e * 1024 + col_e) = hh;
    }
    if (l != 31) {
      // ---- group-local barrier (64 blocks of group g), fence-free ----
      __syncthreads();   // S4: per-wave vmcnt(0) drain -> all h' stores at IF
      if (tid == 0) {
        __hip_atomic_store(&flags[bid], (uint32_t)(ts + 1),
                           __ATOMIC_RELAXED, __HIP_MEMORY_SCOPE_AGENT);
      }
      // prefetch next step's xg while waiting on the barrier (xg constant)
      {
        int ln = l + 1;
#pragma unroll
        for (int a = 0; a < 2; ++a)
#pragma unroll
          for (int b = 0; b < 2; ++b) {
            int q = nw * 2 + b;
            size_t idx = (((size_t)ln * 256 + (q * 64 + s)) * 16 + (g * 4 + mw * 2 + a)) * 64 + lane;
            xp[a][b] = xg[idx];
          }
      }
      // all lanes poll one peer flag each (agent atomic load: IF-coherent)
      while (__hip_atomic_load(&flags[myflag], __ATOMIC_RELAXED,
                               __HIP_MEMORY_SCOPE_AGENT) < (uint32_t)(ts + 1)) {
        __builtin_amdgcn_s_sleep(1);
      }
      __syncthreads();   // S5: whole block saw the barrier
    }
  }
  *(f32x4*)(c_buf + (size_t)R_e * 1024 + col_e) = c4;
}

// ---------------------------------------------------------------------------
// MLP layer 1: hidden = relu(h_last @ W1^T + b1), fp32 VALU.
// ---------------------------------------------------------------------------
__global__ __launch_bounds__(256) void mlp1_kernel(
    const float* __restrict__ h_final, const float* __restrict__ W1,
    const float* __restrict__ b1, float* __restrict__ hidden)
{
  __shared__ float hl[8 * 1024];       // 32 KB
  __shared__ float part[4 * 64 * 8];   // 8 KB
  int tid = threadIdx.x;
  int rb = blockIdx.x;                 // 0..31
  int cb = blockIdx.y;                 // 0..7
  const f32x4* hsrc = (const f32x4*)(h_final + (size_t)rb * 8 * 1024);
  for (int i = tid; i < 2048; i += 256) ((f32x4*)hl)[i] = hsrc[i];
  __syncthreads();
  int cell_l = tid & 63;
  int kq = tid >> 6;                   // k quarter
  int cell = cb * 64 + cell_l;
  float accv[8] = {0,0,0,0,0,0,0,0};
  const f32x4* wrow = (const f32x4*)(W1 + (size_t)cell * 1024) + kq * 64;
  const f32x4* hl4 = (const f32x4*)hl;
  for (int k4 = 0; k4 < 64; ++k4) {
    f32x4 wv = wrow[k4];
    int kidx = kq * 64 + k4;
#pragma unroll
    for (int r = 0; r < 8; ++r) {
      f32x4 hv = hl4[r * 256 + kidx];
      accv[r] += wv[0] * hv[0] + wv[1] * hv[1] + wv[2] * hv[2] + wv[3] * hv[3];
    }
  }
#pragma unroll
  for (int r = 0; r < 8; ++r) part[(kq * 64 + cell_l) * 8 + r] = accv[r];
  __syncthreads();
#pragma unroll
  for (int rr = 0; rr < 2; ++rr) {
    int r = kq * 2 + rr;
    float sum = b1[cell];
    for (int q = 0; q < 4; ++q) sum += part[(q * 64 + cell_l) * 8 + r];
    hidden[(size_t)(rb * 8 + r) * 512 + cell] = fmaxf(sum, 0.0f);
  }
}

// MLP layer 2: out[b] = hidden[b] . W2 + b2
__global__ __launch_bounds__(256) void mlp2_kernel(
    const float* __restrict__ hidden, const float* __restrict__ W2,
    const float* __restrict__ b2, float* __restrict__ out)
{
  __shared__ float w2l[512];
  int tid = threadIdx.x;
  for (int i = tid; i < 512; i += 256) w2l[i] = W2[i];
  __syncthreads();
  const f32x4* hrow = (const f32x4*)(hidden + (size_t)tid * 512);
  const f32x4* w4 = (const f32x4*)w2l;
  float acc = b2[0];
  for (int k = 0; k < 128; ++k) {
    f32x4 a = hrow[k], b = w4[k];
    acc += a[0] * b[0] + a[1] * b[1] + a[2] * b[2] + a[3] * b[3];
  }
  out[tid] = acc;
}

// ---------------------------------------------------------------------------
extern "C" void kernel_launch(void* const* d_in, const int* in_sizes, int n_in,
                              void* d_out, int out_size, void* d_ws, size_t ws_size,
                              hipStream_t stream)
{
  (void)in_sizes; (void)n_in; (void)out_size;
  if (ws_size < WS_NEED) return;   // workspace too small -> loud bench failure

  const float* xt   = (const float*)d_in[0];
  const float* xa   = (const float*)d_in[1];
  const float* xv   = (const float*)d_in[2];
  const float* W_ih = (const float*)d_in[3];
  const float* W_hh = (const float*)d_in[4];
  const float* b_ih = (const float*)d_in[5];
  const float* b_hh = (const float*)d_in[6];
  const float* W1   = (const float*)d_in[7];
  const float* b1   = (const float*)d_in[8];
  const float* W2   = (const float*)d_in[9];
  const float* b2   = (const float*)d_in[10];
  float* out = (float*)d_out;
  char* ws = (char*)d_ws;

  uint32_t* flags   = (uint32_t*)(ws + OFF_FLAGS);
  uint16_t* hb0     = (uint16_t*)(ws + OFF_HBUF0);
  uint16_t* hb1     = (uint16_t*)(ws + OFF_HBUF1);
  float*    c_buf   = (float*)(ws + OFF_CBUF);
  float*    h_final = (float*)(ws + OFF_HFIN);
  float*    hidden  = (float*)(ws + OFF_HID);
  float*    bias    = (float*)(ws + OFF_BIAS);
  uint16_t* whh_p   = (uint16_t*)(ws + OFF_WHH);
  uint16_t* wih_p   = (uint16_t*)(ws + OFF_WIH);
  uint16_t* xb      = (uint16_t*)(ws + OFF_XB);
  uint2*    xg      = (uint2*)(ws + OFF_XG);

  // allow >64KB dynamic LDS for the scan kernel (idempotent, capture-safe)
  hipFuncSetAttribute((const void*)scan_kernel,
                      hipFuncAttributeMaxDynamicSharedMemorySize, 148480);

  // zero flags + h state + c state (ws is poisoned before every launch)
  hipMemsetAsync(ws, 0, ZERO_SPAN, stream);

  pack_xb_kernel  <<<13312, 256, 0, stream>>>(xt, xa, xv, xb);
  pack_whh_kernel <<<2048,  256, 0, stream>>>(W_hh, whh_p);
  pack_wih_kernel <<<832,   256, 0, stream>>>(W_ih, wih_p);
  pack_bias_kernel<<<16,    256, 0, stream>>>(b_ih, b_hh, bias);

  for (int c = 0; c < 8; ++c) {
    xg_gemm_kernel<<<dim3(64, 32), 256, 0, stream>>>(
        (const short8*)xb, (const short8*)wih_p, bias, xg, c);
    scan_kernel<<<256, 256, 148480, stream>>>(
        whh_p, xg, hb0, hb1, c_buf, h_final, flags, c);
  }
  mlp1_kernel<<<dim3(32, 8), 256, 0, stream>>>(h_final, W1, b1, hidden);
  mlp2_kernel<<<1, 256, 0, stream>>>(hidden, W2, b2, out);
}